// Round 6
// baseline (1241.297 us; speedup 1.0000x reference)
//
#include <hip/hip_runtime.h>
#include <cstdint>
#include <cstddef>

#define EDIM  512
#define NROWS 16384
#define NE    8192
#define XQSZ  (NROWS * EDIM)   // 8388608
#define NTILE 64               // 8192 codes / 128 per tile

// workspace byte offsets
#define OFF_ACC   0
#define OFF_Z     4096
#define OFF_C2    (OFF_Z    + NROWS * 4)        // Z: 65536 B
#define OFF_KEYS  (OFF_C2   + NE * 4)           // c2: 32768 B
#define OFF_TMIN  (OFF_KEYS + NROWS * 8)        // keys: 131072 B
#define OFF_CNT   (OFF_TMIN + NROWS * NTILE * 4)// tmin: 4 MB
#define OFF_LIST  (OFF_CNT  + 1024)
#define OFF_XH    (OFF_LIST + NROWS * NTILE * 4)// list: 4 MB
#define OFF_WH    (OFF_XH   + (size_t)NROWS * EDIM * 2)
// total ~= 34 MB (round-5 proved ws >= 151 MB)

typedef __attribute__((ext_vector_type(8)))  short          short8;
typedef __attribute__((ext_vector_type(16))) float          f32x16;
typedef __attribute__((ext_vector_type(4)))  unsigned short u16x4;

// ---------------- rownorm (numpy pairwise order) ----------------
__global__ void k_rownorm(const float* __restrict__ in, float* __restrict__ out, int nrows) {
#pragma clang fp contract(off)
    int row = blockIdx.x * blockDim.x + threadIdx.x;
    if (row >= nrows) return;
    const float* p = in + (size_t)row * EDIM;
    float S[4];
#pragma unroll
    for (int b = 0; b < 4; ++b) {
        const float* q = p + b * 128;
        float r[8];
#pragma unroll
        for (int j = 0; j < 8; ++j) { float v = q[j]; r[j] = v * v; }
        for (int i = 8; i < 128; i += 8) {
#pragma unroll
            for (int j = 0; j < 8; ++j) { float v = q[i + j]; r[j] = r[j] + v * v; }
        }
        S[b] = ((r[0] + r[1]) + (r[2] + r[3])) + ((r[4] + r[5]) + (r[6] + r[7]));
    }
    out[row] = (S[0] + S[1]) + (S[2] + S[3]);
}

// ---------------- hi-bf16 conversion ----------------
__device__ __forceinline__ unsigned short f2bf(float f) {
    unsigned u = __float_as_uint(f);
    return (unsigned short)((u + 0x7FFFu + ((u >> 16) & 1u)) >> 16);
}

__global__ __launch_bounds__(256) void k_split_hi(const float* __restrict__ in,
        unsigned short* __restrict__ outp, int n8) {
    int i = blockIdx.x * 256 + threadIdx.x;
    if (i >= n8) return;
    const float* p = in + (size_t)i * 8;
    float4 a = *(const float4*)p, b = *(const float4*)(p + 4);
    u16x4 h0, h1;
    h0[0]=f2bf(a.x); h0[1]=f2bf(a.y); h0[2]=f2bf(a.z); h0[3]=f2bf(a.w);
    h1[0]=f2bf(b.x); h1[1]=f2bf(b.y); h1[2]=f2bf(b.z); h1[3]=f2bf(b.w);
    unsigned short* o = outp + (size_t)i * 8;
    *(u16x4*)o = h0; *(u16x4*)(o + 4) = h1;
}

// ---------------- pass A: hi-GEMM, per-(row,tile) approx-min ----------------
__device__ __forceinline__ void gld16(const void* g, void* l) {
    __builtin_amdgcn_global_load_lds((const __attribute__((address_space(1))) void*)g,
                                     (__attribute__((address_space(3))) void*)l, 16, 0, 0);
}

#define GBM 128
#define GBN 128
#define GBK 64

__global__ __launch_bounds__(256) void k_argmin_hi(
        const unsigned short* __restrict__ Xh, const unsigned short* __restrict__ Wh,
        const float* __restrict__ c2, unsigned* __restrict__ tmin) {
    __shared__ __align__(16) unsigned short At[GBM * GBK];
    __shared__ __align__(16) unsigned short Bt[GBN * GBK];
    __shared__ unsigned smin[GBM];

    const int tid = threadIdx.x;
    const int lane = tid & 63, wid = tid >> 6;
    const int wr = wid >> 1, wc = wid & 1;

    const int bid = blockIdx.x;
    const int swz = (bid & 7) * 1024 + (bid >> 3);   // 8192 % 8 == 0, bijective
    const int rowtile = swz & 127, codetile = swz >> 7;
    const int row0 = rowtile * GBM, code0 = codetile * GBN;

    if (tid < GBM) smin[tid] = 0xFFFFFFFFu;

    f32x16 acc[2][2];
#pragma unroll
    for (int i = 0; i < 2; ++i)
#pragma unroll
        for (int j = 0; j < 2; ++j)
#pragma unroll
            for (int r = 0; r < 16; ++r) acc[i][j][r] = 0.0f;

    size_t ga[4], gb[4];
#pragma unroll
    for (int i = 0; i < 4; ++i) {
        int chunk = i * 256 + tid;            // 1024 16B-chunks per tile
        int row   = chunk >> 3;               // 8 chunks per row (64 k * 2B)
        int kcs   = (chunk & 7) ^ (row & 7);  // pre-swizzled source chunk
        ga[i] = (size_t)(row0 + row) * EDIM + kcs * 8;
        gb[i] = (size_t)(code0 + row) * EDIM + kcs * 8;
    }

    const int ra0 = wr * 64 + (lane & 31);
    const int rb0 = wc * 64 + (lane & 31);
    const int kh  = lane >> 5;
    const int sa  = ra0 & 7, sb = rb0 & 7;

    for (int kt = 0; kt < EDIM / GBK; ++kt) {
        const size_t ko = (size_t)kt * GBK;
#pragma unroll
        for (int i = 0; i < 4; ++i) {
            gld16(Xh + ga[i] + ko, (char*)At + i * 4096 + wid * 1024);
            gld16(Wh + gb[i] + ko, (char*)Bt + i * 4096 + wid * 1024);
        }
        __syncthreads();
#pragma unroll
        for (int ks = 0; ks < 4; ++ks) {
            const int ch = ks * 2 + kh;
            short8 a0 = *(const short8*)((const char*)At + ra0 * 128        + ((ch ^ sa) * 16));
            short8 a1 = *(const short8*)((const char*)At + (ra0 + 32) * 128 + ((ch ^ sa) * 16));
            short8 b0 = *(const short8*)((const char*)Bt + rb0 * 128        + ((ch ^ sb) * 16));
            short8 b1 = *(const short8*)((const char*)Bt + (rb0 + 32) * 128 + ((ch ^ sb) * 16));
            acc[0][0] = __builtin_amdgcn_mfma_f32_32x32x16_bf16(a0, b0, acc[0][0], 0, 0, 0);
            acc[0][1] = __builtin_amdgcn_mfma_f32_32x32x16_bf16(a0, b1, acc[0][1], 0, 0, 0);
            acc[1][0] = __builtin_amdgcn_mfma_f32_32x32x16_bf16(a1, b0, acc[1][0], 0, 0, 0);
            acc[1][1] = __builtin_amdgcn_mfma_f32_32x32x16_bf16(a1, b1, acc[1][1], 0, 0, 0);
        }
        __syncthreads();
    }

    // approx d (shifted +4 to stay positive): d~ = 4 + c2 - 2*m_hi
    const int j0 = code0 + wc * 64 + (lane & 31);
    const float c20 = c2[j0], c21 = c2[j0 + 32];
#pragma unroll
    for (int mi = 0; mi < 2; ++mi) {
#pragma unroll
        for (int reg = 0; reg < 16; ++reg) {
            const int rl = wr * 64 + mi * 32 + (reg & 3) + 8 * (reg >> 2) + 4 * kh;
            const float d0 = (4.0f + c20) - 2.0f * acc[mi][0][reg];
            const float d1 = (4.0f + c21) - 2.0f * acc[mi][1][reg];
            unsigned u0 = __float_as_uint(d0), u1 = __float_as_uint(d1);
            unsigned u = u0 < u1 ? u0 : u1;   // positive floats: uint order = float order
#pragma unroll
            for (int m = 1; m <= 16; m <<= 1) {
                unsigned o = __shfl_xor(u, m, 64);
                if (o < u) u = o;
            }
            if ((lane & 31) == 0) atomicMin(&smin[rl], u);
        }
    }
    __syncthreads();
    if (tid < GBM) tmin[codetile * NROWS + row0 + tid] = smin[tid];
}

// ---------------- pass B: per-row candidate tile selection ----------------
__global__ __launch_bounds__(256) void k_select(
        const unsigned* __restrict__ tmin, const float* __restrict__ Z,
        int* __restrict__ cnt, int* __restrict__ list) {
    const int row = blockIdx.x * 256 + threadIdx.x;
    unsigned mn = 0xFFFFFFFFu;
    for (int t = 0; t < NTILE; ++t) {
        unsigned v = tmin[t * NROWS + row];
        if (v < mn) mn = v;
    }
    // rigorous: |d~ - d_true| <= 2*(2^-8+2^-8+2^-16)*||x||*||w||, ||w||<=2.7622e-3
    // + f32 tie window (<=1.3e-4 for d<2048) + fp-noise slack
    const float margin = 4.35e-5f * sqrtf(Z[row]) + 1.7e-4f;
    const float thr = __uint_as_float(mn) + margin;
    for (int t = 0; t < NTILE; ++t) {
        if (__uint_as_float(tmin[t * NROWS + row]) <= thr) {
            int p = atomicAdd(&cnt[t], 1);
            list[t * NROWS + p] = row;
        }
    }
}

// ---------------- pass C: exact rescore of candidate tiles ----------------
// grid (NTILE, 8). W quarter (32 codes x 512 f32) staged in LDS with d^c
// swizzle (conflict-free col reads); 8 rows/iter staged in LDS.
// m = sequential f32 fma chain over d (same class as rounds 2/4/5, all of
// which matched np argmin exactly); final d via (Z+c2)-2m in f32 + packed
// key with first-index tiebreak.
__global__ __launch_bounds__(256) void k_rescore(
        const float* __restrict__ x, const float* __restrict__ W,
        const float* __restrict__ Z, const float* __restrict__ c2,
        const int* __restrict__ cnt, const int* __restrict__ list,
        unsigned long long* __restrict__ keys) {
    __shared__ float Wl[32 * 512];   // 64 KB
    __shared__ float Xl[8 * 512];    // 16 KB

    const int tile = blockIdx.x, slice = blockIdx.y;
    const int n = cnt[tile];
    if (n == 0) return;
    const int* rows = list + tile * NROWS;
    const int tid = threadIdx.x;
    const int rs = tid >> 5, c = tid & 31;

    for (int q = 0; q < 4; ++q) {
        // stage W quarter (codes tile*128 + q*32 + [0,32))
        __syncthreads();
        for (int i = tid; i < 32 * 512; i += 256) {
            int cc = i >> 9, d = i & 511;
            Wl[cc * 512 + (d ^ cc)] = W[(size_t)(tile * 128 + q * 32 + cc) * 512 + d];
        }
        __syncthreads();
        const int j = tile * 128 + q * 32 + c;
        const float c2j = c2[j];
        for (int ch = slice; ch * 8 < n; ch += 8) {
            const int ri = ch * 8 + rs;
            const bool valid = ri < n;
            // stage 8 x-rows
            {
                const int sd0 = (tid & 31) * 16;
                if (valid) {
                    const float* xp = x + (size_t)rows[ri] * 512 + sd0;
                    float* xl = Xl + rs * 512 + sd0;
#pragma unroll
                    for (int v = 0; v < 4; ++v)
                        *(float4*)(xl + v * 4) = *(const float4*)(xp + v * 4);
                }
            }
            __syncthreads();
            float m = 0.0f;
#pragma unroll 8
            for (int d = 0; d < 512; ++d)
                m = fmaf(Xl[rs * 512 + d], Wl[c * 512 + (d ^ c)], m);
            unsigned long long k = ~0ull;
            int r = 0;
            if (valid) {
                r = rows[ri];
                const float t1 = Z[r] + c2j;
                const float dd = t1 - 2.0f * m;
                k = (((unsigned long long)__float_as_uint(dd)) << 13) | (unsigned)j;
            }
#pragma unroll
            for (int mm = 1; mm <= 16; mm <<= 1) {
                unsigned long long o = __shfl_xor(k, mm, 64);
                if (o < k) k = o;
            }
            if (c == 0 && valid) atomicMin(&keys[r], k);
            __syncthreads();
        }
    }
}

// ---------------- gather / loss / finalize ----------------
__global__ __launch_bounds__(256) void k_gather(
        const float* __restrict__ x, const float* __restrict__ W,
        const unsigned long long* __restrict__ keys,
        float* __restrict__ out, double* __restrict__ acc) {
    const int row = blockIdx.x;
    const int idx = (int)(keys[row] & 0x1FFFull);

    const float* wrow = W + (size_t)idx * EDIM;
    const float* xrow = x + (size_t)row * EDIM;
    float* orow = out + (size_t)row * EDIM;

    double lsum = 0.0;
    for (int c = threadIdx.x; c < EDIM; c += 256) {
        const float xv = xrow[c];
        const float wv = wrow[c];
        const float t = wv - xv;
        orow[c] = xv + t;
        lsum += (double)t * (double)t;
    }
#pragma unroll
    for (int off = 32; off > 0; off >>= 1) lsum += __shfl_down(lsum, off, 64);
    __shared__ double part[4];
    const int lane = threadIdx.x & 63, w = threadIdx.x >> 6;
    if (lane == 0) part[w] = lsum;
    __syncthreads();
    if (threadIdx.x == 0) {
        atomicAdd(acc, part[0] + part[1] + part[2] + part[3]);
        out[XQSZ + 1 + row] = (float)idx;
    }
}

__global__ void k_finalize(float* __restrict__ out, const double* __restrict__ acc) {
    out[XQSZ] = (float)(0.25 * acc[0] / (double)XQSZ);
}

extern "C" void kernel_launch(void* const* d_in, const int* in_sizes, int n_in,
                              void* d_out, int out_size, void* d_ws, size_t ws_size,
                              hipStream_t stream) {
    const float* x = (const float*)d_in[0];
    const float* W = (const float*)d_in[3];
    float* out = (float*)d_out;
    char* ws = (char*)d_ws;

    double* acc = (double*)(ws + OFF_ACC);
    float* Z    = (float*)(ws + OFF_Z);
    float* c2   = (float*)(ws + OFF_C2);
    unsigned long long* keys = (unsigned long long*)(ws + OFF_KEYS);
    unsigned* tmin = (unsigned*)(ws + OFF_TMIN);
    int* cnt  = (int*)(ws + OFF_CNT);
    int* list = (int*)(ws + OFF_LIST);
    unsigned short* Xh = (unsigned short*)(ws + OFF_XH);
    unsigned short* Wh = (unsigned short*)(ws + OFF_WH);

    hipMemsetAsync(acc, 0, sizeof(double), stream);
    hipMemsetAsync(keys, 0xFF, NROWS * sizeof(unsigned long long), stream);
    hipMemsetAsync(cnt, 0, NTILE * sizeof(int), stream);
    k_rownorm<<<NROWS / 256, 256, 0, stream>>>(x, Z, NROWS);
    k_rownorm<<<NE / 256, 256, 0, stream>>>(W, c2, NE);
    k_split_hi<<<(NROWS * EDIM / 8) / 256, 256, 0, stream>>>(x, Xh, NROWS * EDIM / 8);
    k_split_hi<<<(NE * EDIM / 8) / 256, 256, 0, stream>>>(W, Wh, NE * EDIM / 8);
    k_argmin_hi<<<(NROWS / GBM) * (NE / GBN), 256, 0, stream>>>(Xh, Wh, c2, tmin);
    k_select<<<NROWS / 256, 256, 0, stream>>>(tmin, Z, cnt, list);
    k_rescore<<<dim3(NTILE, 8), 256, 0, stream>>>(x, W, Z, c2, cnt, list, keys);
    k_gather<<<NROWS, 256, 0, stream>>>(x, W, keys, out, acc);
    k_finalize<<<1, 1, 0, stream>>>(out, acc);
}